// Round 6
// baseline (5995.263 us; speedup 1.0000x reference)
//
#include <hip/hip_runtime.h>

typedef unsigned int u32;
typedef unsigned short u16;
typedef unsigned long long u64;

// ---------------- problem constants ----------------
// B=2048, CIN=256, NH=512, NF=112, K=112, NL=50, MC=100, NOUT=200
// out (f32 elements): c_prob [2048,112,100] | y [2048,200] | c_hard [2048,112,100]
#define YOFF  22937600ull
#define CHOFF 23347200ull

// workspace offsets (bytes)
#define OFF_HA    0ull          // 2048*512 f32 = 4,194,304 B
#define OFF_HB    4194304ull    // 2048*512 f32 ; reused as mask buffer (3.28 MB) after last hB read
#define OFF_INTER 8388608ull    // 2048*112 f32 = 917,504 B

// ---------------- threefry2x32 (JAX-compatible, partitionable stream) ----------------
__host__ __device__ inline u32 rotl32_(u32 x, int r) { return (x << r) | (x >> (32 - r)); }
__host__ __device__ inline void tf2x32(u32 k0, u32 k1, u32 c0, u32 c1, u32& o0, u32& o1) {
  u32 ks0 = k0, ks1 = k1, ks2 = k0 ^ k1 ^ 0x1BD11BDAu;
  u32 x0 = c0 + ks0, x1 = c1 + ks1;
  const int RA[4] = {13, 15, 26, 6}, RB[4] = {17, 29, 16, 24};
  for (int i = 0; i < 5; ++i) {
    const int* R = (i & 1) ? RB : RA;
    for (int j = 0; j < 4; ++j) { x0 += x1; x1 = rotl32_(x1, R[j]); x1 ^= x0; }
    switch (i) {
      case 0: x0 += ks1; x1 += ks2 + 1u; break;
      case 1: x0 += ks2; x1 += ks0 + 2u; break;
      case 2: x0 += ks0; x1 += ks1 + 3u; break;
      case 3: x0 += ks1; x1 += ks2 + 4u; break;
      case 4: x0 += ks2; x1 += ks0 + 5u; break;
    }
  }
  o0 = x0; o1 = x1;
}

struct SKeys { u32 v[224]; };  // per-step subkeys: sk_i = tf(key_i,(0,1)); key_{i+1} = tf(key_i,(0,0))

// ---------------- generic f32 GEMM: C = act(A@B + bias) ----------------
// 32x64 tile, BK=32, 256 threads, 2x4 per thread (validated round 5: bitwise-identical k-chain,
// 2x the block count of the 64x64 tile -> better CU coverage on the 6 serial encoder GEMMs).
template <bool DO_LRELU>
__global__ __launch_bounds__(256) void gemm_bias(const float* __restrict__ A,
                                                 const float* __restrict__ Bm,
                                                 const float* __restrict__ bias,
                                                 float* __restrict__ C,
                                                 int M, int N, int K) {
  __shared__ float As[32][33];  // [k][m]
  __shared__ float Bs[32][65];  // [k][n]
  const int bm = blockIdx.y * 32, bn = blockIdx.x * 64;
  const int t = threadIdx.x;
  const int ty = t >> 4, tx = t & 15;      // ty 0..15 (2 rows each), tx 0..15 (4 cols each)
  float acc[2][4] = {};
  for (int k0 = 0; k0 < K; k0 += 32) {
    {
      int e = t;                           // 256 float4 = 32 rows x 8 float4
      int m = e >> 3, k4 = e & 7;
      float4 v = *(const float4*)(A + (size_t)(bm + m) * K + (k0 + k4 * 4));
      As[k4 * 4 + 0][m] = v.x; As[k4 * 4 + 1][m] = v.y;
      As[k4 * 4 + 2][m] = v.z; As[k4 * 4 + 3][m] = v.w;
    }
#pragma unroll
    for (int l = 0; l < 2; ++l) {
      int e = l * 256 + t;
      int k = e >> 4, n4 = e & 15;        // 32 k x 16 float4
      int gn = bn + n4 * 4;
      if (gn < N) {
        float4 v = *(const float4*)(Bm + (size_t)(k0 + k) * N + gn);
        Bs[k][n4 * 4 + 0] = v.x; Bs[k][n4 * 4 + 1] = v.y;
        Bs[k][n4 * 4 + 2] = v.z; Bs[k][n4 * 4 + 3] = v.w;
      } else {
        Bs[k][n4 * 4 + 0] = 0.f; Bs[k][n4 * 4 + 1] = 0.f;
        Bs[k][n4 * 4 + 2] = 0.f; Bs[k][n4 * 4 + 3] = 0.f;
      }
    }
    __syncthreads();
#pragma unroll
    for (int kk = 0; kk < 32; ++kk) {
      float a[2], b[4];
#pragma unroll
      for (int j = 0; j < 2; ++j) a[j] = As[kk][ty * 2 + j];
#pragma unroll
      for (int j = 0; j < 4; ++j) b[j] = Bs[kk][tx * 4 + j];
#pragma unroll
      for (int i = 0; i < 2; ++i)
#pragma unroll
        for (int j = 0; j < 4; ++j) acc[i][j] = fmaf(a[i], b[j], acc[i][j]);
    }
    __syncthreads();
  }
#pragma unroll
  for (int i = 0; i < 2; ++i) {
#pragma unroll
    for (int j = 0; j < 4; ++j) {
      int m = bm + ty * 2 + i, n = bn + tx * 4 + j;
      if (n < N) {
        float s = acc[i][j] + bias[n];
        if (DO_LRELU) { if (s < 0.f) s = 0.01f * s; }
        C[(size_t)m * N + n] = s;
      }
    }
  }
}

// ---------------- base_i[b][h] = inter @ W1_i[:112,:] + b1_i  -> staged into out c_hard region ----------------
// Stored at out[CHOFF + b*11200 + i*100 + h] (h<50). The c_hard region is only rewritten by
// expand_kernel AFTER sample_lds completes, so no aliasing race.
__global__ __launch_bounds__(256) void base_kernel(const float* __restrict__ inter,
                                                   const float* __restrict__ W1,
                                                   const float* __restrict__ pb1,
                                                   float* __restrict__ out) {
  __shared__ float As[112][65];  // [k][b]
  __shared__ float Ws[112][64];  // [k][h], zero-padded h>=50
  const int i = blockIdx.y;
  const int b0 = blockIdx.x * 64;
  const int t = threadIdx.x;
  const int ty = t >> 4, tx = t & 15;
#pragma unroll
  for (int l = 0; l < 7; ++l) {
    int e4 = l * 256 + t;               // < 1792 = 64 rows * 28 float4
    int k4 = e4 % 28, bs = e4 / 28;
    float4 v = *(const float4*)(inter + (size_t)(b0 + bs) * 112 + k4 * 4);
    As[k4 * 4 + 0][bs] = v.x; As[k4 * 4 + 1][bs] = v.y;
    As[k4 * 4 + 2][bs] = v.z; As[k4 * 4 + 3][bs] = v.w;
  }
#pragma unroll
  for (int l = 0; l < 28; ++l) {
    int e = l * 256 + t;                // < 7168 = 112*64
    int r = e >> 6, c = e & 63;
    Ws[r][c] = (c < 50) ? W1[(size_t)i * 11200 + r * 50 + c] : 0.f;
  }
  __syncthreads();
  float acc[4][4] = {};
  for (int kk = 0; kk < 112; ++kk) {
    float a[4], b[4];
#pragma unroll
    for (int j = 0; j < 4; ++j) { a[j] = As[kk][ty * 4 + j]; b[j] = Ws[kk][tx * 4 + j]; }
#pragma unroll
    for (int ii = 0; ii < 4; ++ii)
#pragma unroll
      for (int j = 0; j < 4; ++j) acc[ii][j] = fmaf(a[ii], b[j], acc[ii][j]);
  }
#pragma unroll
  for (int ii = 0; ii < 4; ++ii) {
#pragma unroll
    for (int j = 0; j < 4; ++j) {
      int b = b0 + ty * 4 + ii, h = tx * 4 + j;
      if (h < 50) {
        out[CHOFF + (size_t)b * 11200 + (size_t)i * 100 + h] = acc[ii][j] + pb1[i * 50 + h];
      }
    }
  }
}

// ---------------- sequential concept sampling: ONE THREAD PER PAIR + LDS-staged broadcast weights ----------
// 800 blocks x 256 threads = 204800 pairs exactly (all threads active -> barrier-safe).
// The weight rows (wave-uniform broadcast values) move off the SGPR file (whose 102-reg size
// forced single-buffered 50-dword s_loads = the round-0 stall) into LDS:
//   iteration i: [issue global loads of step i+1's feedback rows -> stg regs]  (latency hides
//                under compute)  ->  [compute step i from LDS buf[i&1]: r-loop of ds_read_b128
//                broadcast rows (same addr all lanes = conflict-free, deep lgkmcnt pipelining)
//                + verbatim round-0 tail]  ->  [ds_write stg -> buf[(i+1)&1]]  -> barrier.
// One barrier/step; buffers alternate; step i's rows were staged during step i-1. Per-h fmaf
// chains (r ascending, two mask segments), ordered 50-term dot, sigmoid, threefry are VERBATIM
// round-0 arithmetic -> sampling bits cannot flip.
// Row stride 52 floats keeps ds_read_b128 16B-aligned; LDS = 2*112*52*4 = 46.6 KB -> 3 blocks/CU
// (= the grid's 3.125 blocks/CU, so no residency loss).
// History masks go to the dead hB workspace; expand_kernel materializes c_hard afterwards.
#define SROW 52
#define SBUF (112 * SROW)
__global__ __launch_bounds__(256, 3) void sample_lds(const float* __restrict__ W1,
                                                     const float* __restrict__ W2,
                                                     const float* __restrict__ b2v,
                                                     float* __restrict__ out,
                                                     u32* __restrict__ masks, SKeys sks) {
  __shared__ float wlds[2 * SBUF];
  const int t = threadIdx.x;
  const int p = blockIdx.x * 256 + t;          // pair id = b*100 + m; exact cover 800*256=204800
  const int b = p / 100;
  const int m = p - b * 100;
  const float* __restrict__ baserow = out + CHOFF + (size_t)b * 11200;  // + i*100 + h
  u64 lo = 0, hi = 0;
  float acc[50];
  float stg[22];

  for (int i = 0; i < 112; ++i) {
    // ---- (1) issue global loads for step i+1's feedback rows (0..i of W1[i+1]) ----
    const int D = (i + 1) * 50;                 // dwords to stage (<= 5600)
    if (i < 111) {
      const float* __restrict__ Wn = W1 + (size_t)(i + 1) * 11200 + 5600;
#pragma unroll
      for (int l = 0; l < 22; ++l) {
        int e = t + l * 256;
        if (e < D) stg[l] = Wn[e];
      }
    }
    // ---- (2) compute step i from LDS buf[i&1] ----
#pragma unroll
    for (int h = 0; h < 50; ++h) acc[h] = 0.f;
    {
      const float* __restrict__ Lb = wlds + (i & 1) * SBUF;
      int r = 0;
      int r1 = (i < 64) ? i : 64;
      u64 cm = lo;
      for (; r < r1; ++r) {
        float c = (cm & 1ull) ? 1.f : 0.f;
        cm >>= 1;
        const float4* __restrict__ w4 = (const float4*)(Lb + r * SROW);
#pragma unroll
        for (int j = 0; j < 12; ++j) {
          float4 q = w4[j];
          acc[4 * j + 0] = fmaf(c, q.x, acc[4 * j + 0]);
          acc[4 * j + 1] = fmaf(c, q.y, acc[4 * j + 1]);
          acc[4 * j + 2] = fmaf(c, q.z, acc[4 * j + 2]);
          acc[4 * j + 3] = fmaf(c, q.w, acc[4 * j + 3]);
        }
        float2 e2 = *(const float2*)(Lb + r * SROW + 48);
        acc[48] = fmaf(c, e2.x, acc[48]);
        acc[49] = fmaf(c, e2.y, acc[49]);
      }
      cm = hi;
      for (; r < i; ++r) {
        float c = (cm & 1ull) ? 1.f : 0.f;
        cm >>= 1;
        const float4* __restrict__ w4 = (const float4*)(Lb + r * SROW);
#pragma unroll
        for (int j = 0; j < 12; ++j) {
          float4 q = w4[j];
          acc[4 * j + 0] = fmaf(c, q.x, acc[4 * j + 0]);
          acc[4 * j + 1] = fmaf(c, q.y, acc[4 * j + 1]);
          acc[4 * j + 2] = fmaf(c, q.z, acc[4 * j + 2]);
          acc[4 * j + 3] = fmaf(c, q.w, acc[4 * j + 3]);
        }
        float2 e2 = *(const float2*)(Lb + r * SROW + 48);
        acc[48] = fmaf(c, e2.x, acc[48]);
        acc[49] = fmaf(c, e2.y, acc[49]);
      }
    }
    // ---- tail: verbatim round-0 arithmetic ----
    {
      const float* __restrict__ w2 = W2 + i * 50;      // wave-uniform -> s_load
      const float* bs = baserow + (size_t)i * 100;     // per-lane, mostly L1-hit
      float s = 0.f;
#pragma unroll
      for (int h = 0; h < 50; ++h) {
        float v = acc[h] + bs[h];
        if (v < 0.f) v = 0.01f * v;
        s = fmaf(v, w2[h], s);
      }
      float l = s + b2v[i];
      float pr = 1.f / (1.f + expf(-l));
      u32 a0, a1;
      tf2x32(sks.v[2 * i], sks.v[2 * i + 1], 0u, (u32)p, a0, a1);
      u32 fb = ((a0 ^ a1) >> 9) | 0x3F800000u;
      float uu; __builtin_memcpy(&uu, &fb, 4); uu -= 1.f;
      u64 sbit = (uu < pr) ? 1ull : 0ull;
      out[(size_t)b * 11200 + (size_t)i * 100 + m] = pr;   // c_prob (owned cell)
      if (i < 64) lo |= sbit << i; else hi |= sbit << (i - 64);
    }
    // ---- (3) write staged rows into buf[(i+1)&1], then barrier ----
    if (i < 111) {
      float* __restrict__ Ln = wlds + ((i + 1) & 1) * SBUF;
#pragma unroll
      for (int l = 0; l < 22; ++l) {
        int e = t + l * 256;
        if (e < D) {
          int r = e / 50, c = e - r * 50;
          Ln[r * SROW + c] = stg[l];
        }
      }
    }
    __syncthreads();
  }
  // ---- store history masks, coalesced, into dead hB workspace ----
  u32* mp = masks + (size_t)p * 4;
  mp[0] = (u32)lo; mp[1] = (u32)(lo >> 32);
  mp[2] = (u32)hi; mp[3] = (u32)(hi >> 32);
}

// ---------------- expand masks -> c_hard (memory-bound) ----------------
__global__ __launch_bounds__(256) void expand_kernel(const u32* __restrict__ masks,
                                                     float* __restrict__ out) {
  __shared__ u32 mW[100][4];
  const int b = blockIdx.x;
  const int t = threadIdx.x;
  if (t < 100) {
    const u32* mp = masks + ((size_t)b * 100 + t) * 4;
    mW[t][0] = mp[0]; mW[t][1] = mp[1]; mW[t][2] = mp[2]; mW[t][3] = mp[3];
  }
  __syncthreads();
  for (int e = t; e < 11200; e += 256) {
    int i = e / 100, m = e - i * 100;
    u32 word = mW[m][i >> 5];
    out[CHOFF + (size_t)b * 11200 + e] = (float)((word >> (i & 31)) & 1u);
  }
}

// ---------------- head: logits -> softmax -> mean over m -> log ----------------
__global__ __launch_bounds__(256) void head_kernel(const float* __restrict__ HW,
                                                   const float* __restrict__ hb,
                                                   float* __restrict__ out) {
  __shared__ unsigned char cS[100][116];
  __shared__ float lgS[50][201];
  const int b = blockIdx.x;
  const int t = threadIdx.x;
  for (int e = t; e < 11200; e += 256) {
    int k = e / 100, m = e - k * 100;
    cS[m][k] = (out[CHOFF + (size_t)b * 11200 + (size_t)k * 100 + m] != 0.f) ? 1 : 0;
  }
  __syncthreads();
  float pacc = 0.f;
  for (int mh = 0; mh < 2; ++mh) {
    for (int l = 0; l < 3; ++l) {
      int tile = l * 256 + t;
      if (tile < 625) {                    // 25 o-chunks x 25 m-chunks
        int o0 = (tile % 25) * 8;
        int m0 = (tile / 25) * 2;
        float acc[2][8] = {};
        for (int k = 0; k < 112; ++k) {
          float4 wa = *(const float4*)(HW + (size_t)k * 200 + o0);
          float4 wb = *(const float4*)(HW + (size_t)k * 200 + o0 + 4);
          float w[8] = {wa.x, wa.y, wa.z, wa.w, wb.x, wb.y, wb.z, wb.w};
          float c0 = (float)cS[mh * 50 + m0][k];
          float c1 = (float)cS[mh * 50 + m0 + 1][k];
#pragma unroll
          for (int jo = 0; jo < 8; ++jo) {
            acc[0][jo] = fmaf(c0, w[jo], acc[0][jo]);
            acc[1][jo] = fmaf(c1, w[jo], acc[1][jo]);
          }
        }
#pragma unroll
        for (int im = 0; im < 2; ++im)
#pragma unroll
          for (int jo = 0; jo < 8; ++jo) {
            int o = o0 + jo;
            lgS[m0 + im][o] = acc[im][jo] + hb[o];
          }
      }
    }
    __syncthreads();
    if (t < 50) {
      int m = t;
      float mx = -3.0e38f;
      for (int o = 0; o < 200; ++o) mx = fmaxf(mx, lgS[m][o]);
      float s = 0.f;
      for (int o = 0; o < 200; ++o) {
        float e = expf(lgS[m][o] - mx);
        lgS[m][o] = e; s += e;
      }
      float inv = 1.f / s;
      for (int o = 0; o < 200; ++o) lgS[m][o] = lgS[m][o] * inv;
    }
    __syncthreads();
    if (t < 200) { for (int m = 0; m < 50; ++m) pacc += lgS[m][t]; }
    __syncthreads();
  }
  if (t < 200) {
    out[YOFF + (size_t)b * 200 + t] = logf(pacc / 100.f + 1e-6f);
  }
}

// ---------------- launcher ----------------
extern "C" void kernel_launch(void* const* d_in, const int* in_sizes, int n_in,
                              void* d_out, int out_size, void* d_ws, size_t ws_size,
                              hipStream_t stream) {
  const float* x    = (const float*)d_in[0];
  const float* Win  = (const float*)d_in[1];
  const float* bin  = (const float*)d_in[2];
  const float* Wh   = (const float*)d_in[3];
  const float* bh   = (const float*)d_in[4];
  const float* Wout = (const float*)d_in[5];
  const float* bout = (const float*)d_in[6];
  const float* pW1  = (const float*)d_in[7];
  const float* pb1  = (const float*)d_in[8];
  const float* pW2  = (const float*)d_in[9];
  const float* pb2  = (const float*)d_in[10];
  const float* hW   = (const float*)d_in[11];
  const float* hb   = (const float*)d_in[12];
  float* out = (float*)d_out;
  char* ws = (char*)d_ws;

  float* hA     = (float*)(ws + OFF_HA);
  float* hB     = (float*)(ws + OFF_HB);
  float* interB = (float*)(ws + OFF_INTER);
  u32*   masks  = (u32*)(ws + OFF_HB);     // alias: dead after last hB-reading gemm

  gemm_bias<true ><<<dim3(8, 64), 256, 0, stream>>>(x,  Win,             bin,          hA,     2048, 512, 256);
  gemm_bias<true ><<<dim3(8, 64), 256, 0, stream>>>(hA, Wh + 0 * 262144, bh + 0 * 512, hB,     2048, 512, 512);
  gemm_bias<true ><<<dim3(8, 64), 256, 0, stream>>>(hB, Wh + 1 * 262144, bh + 1 * 512, hA,     2048, 512, 512);
  gemm_bias<true ><<<dim3(8, 64), 256, 0, stream>>>(hA, Wh + 2 * 262144, bh + 2 * 512, hB,     2048, 512, 512);
  gemm_bias<true ><<<dim3(8, 64), 256, 0, stream>>>(hB, Wh + 3 * 262144, bh + 3 * 512, hA,     2048, 512, 512);
  gemm_bias<false><<<dim3(2, 64), 256, 0, stream>>>(hA, Wout,            bout,         interB, 2048, 112, 512);

  base_kernel<<<dim3(32, 112), 256, 0, stream>>>(interB, pW1, pb1, out);

  // host-side key chain: key(42)=(0,42); partitionable split: key'=tf(key,(0,0)), sk=tf(key,(0,1))
  SKeys sks;
  {
    u32 k0 = 0u, k1 = 42u;
    for (int i = 0; i < 112; ++i) {
      u32 nk0, nk1, s0, s1;
      tf2x32(k0, k1, 0u, 0u, nk0, nk1);
      tf2x32(k0, k1, 0u, 1u, s0, s1);
      sks.v[2 * i] = s0; sks.v[2 * i + 1] = s1;
      k0 = nk0; k1 = nk1;
    }
  }
  sample_lds<<<800, 256, 0, stream>>>(pW1, pW2, pb2, out, masks, sks);
  expand_kernel<<<2048, 256, 0, stream>>>(masks, out);

  head_kernel<<<2048, 256, 0, stream>>>(hW, hb, out);
}

// Round 9
// 3652.412 us; speedup vs baseline: 1.6415x; 1.6415x over previous
//
#include <hip/hip_runtime.h>

typedef unsigned int u32;
typedef unsigned short u16;
typedef unsigned long long u64;

// ---------------- problem constants ----------------
// B=2048, CIN=256, NH=512, NF=112, K=112, NL=50, MC=100, NOUT=200
// out (f32 elements): c_prob [2048,112,100] | y [2048,200] | c_hard [2048,112,100]
#define YOFF  22937600ull
#define CHOFF 23347200ull

// workspace offsets (bytes)
#define OFF_HA    0ull          // 2048*512 f32 = 4,194,304 B
#define OFF_HB    4194304ull    // 2048*512 f32 ; reused as mask buffer (3.28 MB) after last hB read
#define OFF_INTER 8388608ull    // 2048*112 f32 = 917,504 B

// ---------------- threefry2x32 (JAX-compatible, partitionable stream) ----------------
__host__ __device__ inline u32 rotl32_(u32 x, int r) { return (x << r) | (x >> (32 - r)); }
__host__ __device__ inline void tf2x32(u32 k0, u32 k1, u32 c0, u32 c1, u32& o0, u32& o1) {
  u32 ks0 = k0, ks1 = k1, ks2 = k0 ^ k1 ^ 0x1BD11BDAu;
  u32 x0 = c0 + ks0, x1 = c1 + ks1;
  const int RA[4] = {13, 15, 26, 6}, RB[4] = {17, 29, 16, 24};
  for (int i = 0; i < 5; ++i) {
    const int* R = (i & 1) ? RB : RA;
    for (int j = 0; j < 4; ++j) { x0 += x1; x1 = rotl32_(x1, R[j]); x1 ^= x0; }
    switch (i) {
      case 0: x0 += ks1; x1 += ks2 + 1u; break;
      case 1: x0 += ks2; x1 += ks0 + 2u; break;
      case 2: x0 += ks0; x1 += ks1 + 3u; break;
      case 3: x0 += ks1; x1 += ks2 + 4u; break;
      case 4: x0 += ks2; x1 += ks0 + 5u; break;
    }
  }
  o0 = x0; o1 = x1;
}

struct SKeys { u32 v[224]; };  // per-step subkeys: sk_i = tf(key_i,(0,1)); key_{i+1} = tf(key_i,(0,0))

// ---------------- generic f32 GEMM: C = act(A@B + bias) ----------------
// 32x64 tile, BK=32, 256 threads, 2x4 per thread (validated round 5: bitwise-identical k-chain,
// 2x the block count of the 64x64 tile -> better CU coverage on the 6 serial encoder GEMMs).
template <bool DO_LRELU>
__global__ __launch_bounds__(256) void gemm_bias(const float* __restrict__ A,
                                                 const float* __restrict__ Bm,
                                                 const float* __restrict__ bias,
                                                 float* __restrict__ C,
                                                 int M, int N, int K) {
  __shared__ float As[32][33];  // [k][m]
  __shared__ float Bs[32][65];  // [k][n]
  const int bm = blockIdx.y * 32, bn = blockIdx.x * 64;
  const int t = threadIdx.x;
  const int ty = t >> 4, tx = t & 15;      // ty 0..15 (2 rows each), tx 0..15 (4 cols each)
  float acc[2][4] = {};
  for (int k0 = 0; k0 < K; k0 += 32) {
    {
      int e = t;                           // 256 float4 = 32 rows x 8 float4
      int m = e >> 3, k4 = e & 7;
      float4 v = *(const float4*)(A + (size_t)(bm + m) * K + (k0 + k4 * 4));
      As[k4 * 4 + 0][m] = v.x; As[k4 * 4 + 1][m] = v.y;
      As[k4 * 4 + 2][m] = v.z; As[k4 * 4 + 3][m] = v.w;
    }
#pragma unroll
    for (int l = 0; l < 2; ++l) {
      int e = l * 256 + t;
      int k = e >> 4, n4 = e & 15;        // 32 k x 16 float4
      int gn = bn + n4 * 4;
      if (gn < N) {
        float4 v = *(const float4*)(Bm + (size_t)(k0 + k) * N + gn);
        Bs[k][n4 * 4 + 0] = v.x; Bs[k][n4 * 4 + 1] = v.y;
        Bs[k][n4 * 4 + 2] = v.z; Bs[k][n4 * 4 + 3] = v.w;
      } else {
        Bs[k][n4 * 4 + 0] = 0.f; Bs[k][n4 * 4 + 1] = 0.f;
        Bs[k][n4 * 4 + 2] = 0.f; Bs[k][n4 * 4 + 3] = 0.f;
      }
    }
    __syncthreads();
#pragma unroll
    for (int kk = 0; kk < 32; ++kk) {
      float a[2], b[4];
#pragma unroll
      for (int j = 0; j < 2; ++j) a[j] = As[kk][ty * 2 + j];
#pragma unroll
      for (int j = 0; j < 4; ++j) b[j] = Bs[kk][tx * 4 + j];
#pragma unroll
      for (int i = 0; i < 2; ++i)
#pragma unroll
        for (int j = 0; j < 4; ++j) acc[i][j] = fmaf(a[i], b[j], acc[i][j]);
    }
    __syncthreads();
  }
#pragma unroll
  for (int i = 0; i < 2; ++i) {
#pragma unroll
    for (int j = 0; j < 4; ++j) {
      int m = bm + ty * 2 + i, n = bn + tx * 4 + j;
      if (n < N) {
        float s = acc[i][j] + bias[n];
        if (DO_LRELU) { if (s < 0.f) s = 0.01f * s; }
        C[(size_t)m * N + n] = s;
      }
    }
  }
}

// ---------------- base_i[b][h] = inter @ W1_i[:112,:] + b1_i  -> staged into out c_hard region ----------------
// Stored at out[CHOFF + b*11200 + i*100 + h] (h<50). The c_hard region is only rewritten by
// expand_kernel AFTER sample_kernel6 completes, so no aliasing race.
__global__ __launch_bounds__(256) void base_kernel(const float* __restrict__ inter,
                                                   const float* __restrict__ W1,
                                                   const float* __restrict__ pb1,
                                                   float* __restrict__ out) {
  __shared__ float As[112][65];  // [k][b]
  __shared__ float Ws[112][64];  // [k][h], zero-padded h>=50
  const int i = blockIdx.y;
  const int b0 = blockIdx.x * 64;
  const int t = threadIdx.x;
  const int ty = t >> 4, tx = t & 15;
#pragma unroll
  for (int l = 0; l < 7; ++l) {
    int e4 = l * 256 + t;               // < 1792 = 64 rows * 28 float4
    int k4 = e4 % 28, bs = e4 / 28;
    float4 v = *(const float4*)(inter + (size_t)(b0 + bs) * 112 + k4 * 4);
    As[k4 * 4 + 0][bs] = v.x; As[k4 * 4 + 1][bs] = v.y;
    As[k4 * 4 + 2][bs] = v.z; As[k4 * 4 + 3][bs] = v.w;
  }
#pragma unroll
  for (int l = 0; l < 28; ++l) {
    int e = l * 256 + t;                // < 7168 = 112*64
    int r = e >> 6, c = e & 63;
    Ws[r][c] = (c < 50) ? W1[(size_t)i * 11200 + r * 50 + c] : 0.f;
  }
  __syncthreads();
  float acc[4][4] = {};
  for (int kk = 0; kk < 112; ++kk) {
    float a[4], b[4];
#pragma unroll
    for (int j = 0; j < 4; ++j) { a[j] = As[kk][ty * 4 + j]; b[j] = Ws[kk][tx * 4 + j]; }
#pragma unroll
    for (int ii = 0; ii < 4; ++ii)
#pragma unroll
      for (int j = 0; j < 4; ++j) acc[ii][j] = fmaf(a[ii], b[j], acc[ii][j]);
  }
#pragma unroll
  for (int ii = 0; ii < 4; ++ii) {
#pragma unroll
    for (int j = 0; j < 4; ++j) {
      int b = b0 + ty * 4 + ii, h = tx * 4 + j;
      if (h < 50) {
        out[CHOFF + (size_t)b * 11200 + (size_t)i * 100 + h] = acc[ii][j] + pb1[i * 50 + h];
      }
    }
  }
}

// ---------------- sequential concept sampling: ONE THREAD PER PAIR, half-row s_load pipeline ------------
// 800 blocks x 256 threads = 204800 pairs exactly (all lanes active; uniform 3.125 blocks/CU vs
// round-0's 410x512 imbalance). Round-0 skeleton: no barriers, no LDS, wave-uniform weight rows
// via the scalar pipe. The ONE change vs round-0's r-loop: rows are consumed as two 25-dword
// halves with unroll-2, so the scheduler sees four independent 25-dword s_load chunks per
// unrolled iteration and can keep 2-3 in flight inside the 102-SGPR file (round-0's monolithic
// 50-dword row forced single-buffering = the measured 50% stall; round-5 proved 25-dword
// granularity lifts VALU duty to ~59%). Splitting h does NOT reorder any acc[h] chain: each
// chain still receives its fmaf at ascending r — bitwise identical to the validated kernel.
// Tail (lrelu -> ordered 50-term dot -> sigmoid -> threefry -> compare) is VERBATIM round-0.
// History masks go to the dead hB workspace; expand_kernel materializes c_hard afterwards.
__global__ __launch_bounds__(256) void sample_kernel6(const float* __restrict__ W1,
                                                      const float* __restrict__ W2,
                                                      const float* __restrict__ b2v,
                                                      float* __restrict__ out,
                                                      u32* __restrict__ masks, SKeys sks) {
  const int t = threadIdx.x;
  const int p = blockIdx.x * 256 + t;          // pair id = b*100 + m; exact cover 800*256=204800
  const int b = p / 100;
  const int m = p - b * 100;
  const float* __restrict__ baserow = out + CHOFF + (size_t)b * 11200;  // + i*100 + h
  u64 lo = 0, hi = 0;

  for (int i = 0; i < 112; ++i) {
    const float* __restrict__ Wi = W1 + (size_t)i * 11200 + 5600;  // feedback block, wave-uniform
    float acc[50];
#pragma unroll
    for (int h = 0; h < 50; ++h) acc[h] = 0.f;
    // ---- feedback r-loop: acc[h] += c_r * W[r][h], exact ascending-r order per h-chain ----
    {
      int r = 0;
      int r1 = (i < 64) ? i : 64;
      u64 cm = lo;
#pragma unroll 2
      for (; r < r1; ++r) {
        float c = (cm & 1ull) ? 1.f : 0.f;
        cm >>= 1;
        const float* __restrict__ wrA = Wi + r * 50;       // uniform -> s_load x25
        const float* __restrict__ wrB = wrA + 25;          // uniform -> s_load x25
#pragma unroll
        for (int h = 0; h < 25; ++h) acc[h] = fmaf(c, wrA[h], acc[h]);
#pragma unroll
        for (int h = 0; h < 25; ++h) acc[25 + h] = fmaf(c, wrB[h], acc[25 + h]);
      }
      cm = hi;
#pragma unroll 2
      for (; r < i; ++r) {
        float c = (cm & 1ull) ? 1.f : 0.f;
        cm >>= 1;
        const float* __restrict__ wrA = Wi + r * 50;
        const float* __restrict__ wrB = wrA + 25;
#pragma unroll
        for (int h = 0; h < 25; ++h) acc[h] = fmaf(c, wrA[h], acc[h]);
#pragma unroll
        for (int h = 0; h < 25; ++h) acc[25 + h] = fmaf(c, wrB[h], acc[25 + h]);
      }
    }
    // ---- tail: verbatim round-0 arithmetic ----
    const float* __restrict__ w2 = W2 + i * 50;    // wave-uniform -> s_load
    const float* bs = baserow + (size_t)i * 100;   // per-lane, 1-2 distinct lines per wave
    float s = 0.f;
#pragma unroll
    for (int h = 0; h < 50; ++h) {
      float v = acc[h] + bs[h];
      if (v < 0.f) v = 0.01f * v;
      s = fmaf(v, w2[h], s);
    }
    float l = s + b2v[i];
    float pr = 1.f / (1.f + expf(-l));
    // JAX f32 uniform: bits = o0^o1 of tf(sk_i,(0,p)); u = bitcast((bits>>9)|0x3F800000)-1
    u32 a0, a1;
    tf2x32(sks.v[2 * i], sks.v[2 * i + 1], 0u, (u32)p, a0, a1);
    u32 fb = ((a0 ^ a1) >> 9) | 0x3F800000u;
    float uu; __builtin_memcpy(&uu, &fb, 4); uu -= 1.f;
    u64 sbit = (uu < pr) ? 1ull : 0ull;
    out[(size_t)b * 11200 + (size_t)i * 100 + m] = pr;   // c_prob (owned cell)
    if (i < 64) lo |= sbit << i; else hi |= sbit << (i - 64);
  }
  // ---- store history masks, coalesced, into dead hB workspace ----
  u32* mp = masks + (size_t)p * 4;
  mp[0] = (u32)lo; mp[1] = (u32)(lo >> 32);
  mp[2] = (u32)hi; mp[3] = (u32)(hi >> 32);
}

// ---------------- expand masks -> c_hard (memory-bound) ----------------
__global__ __launch_bounds__(256) void expand_kernel(const u32* __restrict__ masks,
                                                     float* __restrict__ out) {
  __shared__ u32 mW[100][4];
  const int b = blockIdx.x;
  const int t = threadIdx.x;
  if (t < 100) {
    const u32* mp = masks + ((size_t)b * 100 + t) * 4;
    mW[t][0] = mp[0]; mW[t][1] = mp[1]; mW[t][2] = mp[2]; mW[t][3] = mp[3];
  }
  __syncthreads();
  for (int e = t; e < 11200; e += 256) {
    int i = e / 100, m = e - i * 100;
    u32 word = mW[m][i >> 5];
    out[CHOFF + (size_t)b * 11200 + e] = (float)((word >> (i & 31)) & 1u);
  }
}

// ---------------- head: logits -> softmax -> mean over m -> log ----------------
__global__ __launch_bounds__(256) void head_kernel(const float* __restrict__ HW,
                                                   const float* __restrict__ hb,
                                                   float* __restrict__ out) {
  __shared__ unsigned char cS[100][116];
  __shared__ float lgS[50][201];
  const int b = blockIdx.x;
  const int t = threadIdx.x;
  for (int e = t; e < 11200; e += 256) {
    int k = e / 100, m = e - k * 100;
    cS[m][k] = (out[CHOFF + (size_t)b * 11200 + (size_t)k * 100 + m] != 0.f) ? 1 : 0;
  }
  __syncthreads();
  float pacc = 0.f;
  for (int mh = 0; mh < 2; ++mh) {
    for (int l = 0; l < 3; ++l) {
      int tile = l * 256 + t;
      if (tile < 625) {                    // 25 o-chunks x 25 m-chunks
        int o0 = (tile % 25) * 8;
        int m0 = (tile / 25) * 2;
        float acc[2][8] = {};
        for (int k = 0; k < 112; ++k) {
          float4 wa = *(const float4*)(HW + (size_t)k * 200 + o0);
          float4 wb = *(const float4*)(HW + (size_t)k * 200 + o0 + 4);
          float w[8] = {wa.x, wa.y, wa.z, wa.w, wb.x, wb.y, wb.z, wb.w};
          float c0 = (float)cS[mh * 50 + m0][k];
          float c1 = (float)cS[mh * 50 + m0 + 1][k];
#pragma unroll
          for (int jo = 0; jo < 8; ++jo) {
            acc[0][jo] = fmaf(c0, w[jo], acc[0][jo]);
            acc[1][jo] = fmaf(c1, w[jo], acc[1][jo]);
          }
        }
#pragma unroll
        for (int im = 0; im < 2; ++im)
#pragma unroll
          for (int jo = 0; jo < 8; ++jo) {
            int o = o0 + jo;
            lgS[m0 + im][o] = acc[im][jo] + hb[o];
          }
      }
    }
    __syncthreads();
    if (t < 50) {
      int m = t;
      float mx = -3.0e38f;
      for (int o = 0; o < 200; ++o) mx = fmaxf(mx, lgS[m][o]);
      float s = 0.f;
      for (int o = 0; o < 200; ++o) {
        float e = expf(lgS[m][o] - mx);
        lgS[m][o] = e; s += e;
      }
      float inv = 1.f / s;
      for (int o = 0; o < 200; ++o) lgS[m][o] = lgS[m][o] * inv;
    }
    __syncthreads();
    if (t < 200) { for (int m = 0; m < 50; ++m) pacc += lgS[m][t]; }
    __syncthreads();
  }
  if (t < 200) {
    out[YOFF + (size_t)b * 200 + t] = logf(pacc / 100.f + 1e-6f);
  }
}

// ---------------- launcher ----------------
extern "C" void kernel_launch(void* const* d_in, const int* in_sizes, int n_in,
                              void* d_out, int out_size, void* d_ws, size_t ws_size,
                              hipStream_t stream) {
  const float* x    = (const float*)d_in[0];
  const float* Win  = (const float*)d_in[1];
  const float* bin  = (const float*)d_in[2];
  const float* Wh   = (const float*)d_in[3];
  const float* bh   = (const float*)d_in[4];
  const float* Wout = (const float*)d_in[5];
  const float* bout = (const float*)d_in[6];
  const float* pW1  = (const float*)d_in[7];
  const float* pb1  = (const float*)d_in[8];
  const float* pW2  = (const float*)d_in[9];
  const float* pb2  = (const float*)d_in[10];
  const float* hW   = (const float*)d_in[11];
  const float* hb   = (const float*)d_in[12];
  float* out = (float*)d_out;
  char* ws = (char*)d_ws;

  float* hA     = (float*)(ws + OFF_HA);
  float* hB     = (float*)(ws + OFF_HB);
  float* interB = (float*)(ws + OFF_INTER);
  u32*   masks  = (u32*)(ws + OFF_HB);     // alias: dead after last hB-reading gemm

  gemm_bias<true ><<<dim3(8, 64), 256, 0, stream>>>(x,  Win,             bin,          hA,     2048, 512, 256);
  gemm_bias<true ><<<dim3(8, 64), 256, 0, stream>>>(hA, Wh + 0 * 262144, bh + 0 * 512, hB,     2048, 512, 512);
  gemm_bias<true ><<<dim3(8, 64), 256, 0, stream>>>(hB, Wh + 1 * 262144, bh + 1 * 512, hA,     2048, 512, 512);
  gemm_bias<true ><<<dim3(8, 64), 256, 0, stream>>>(hA, Wh + 2 * 262144, bh + 2 * 512, hB,     2048, 512, 512);
  gemm_bias<true ><<<dim3(8, 64), 256, 0, stream>>>(hB, Wh + 3 * 262144, bh + 3 * 512, hA,     2048, 512, 512);
  gemm_bias<false><<<dim3(2, 64), 256, 0, stream>>>(hA, Wout,            bout,         interB, 2048, 112, 512);

  base_kernel<<<dim3(32, 112), 256, 0, stream>>>(interB, pW1, pb1, out);

  // host-side key chain: key(42)=(0,42); partitionable split: key'=tf(key,(0,0)), sk=tf(key,(0,1))
  SKeys sks;
  {
    u32 k0 = 0u, k1 = 42u;
    for (int i = 0; i < 112; ++i) {
      u32 nk0, nk1, s0, s1;
      tf2x32(k0, k1, 0u, 0u, nk0, nk1);
      tf2x32(k0, k1, 0u, 1u, s0, s1);
      sks.v[2 * i] = s0; sks.v[2 * i + 1] = s1;
      k0 = nk0; k1 = nk1;
    }
  }
  sample_kernel6<<<800, 256, 0, stream>>>(pW1, pW2, pb2, out, masks, sks);
  expand_kernel<<<2048, 256, 0, stream>>>(masks, out);

  head_kernel<<<2048, 256, 0, stream>>>(hW, hb, out);
}